// Round 2
// baseline (982.247 us; speedup 1.0000x reference)
//
#include <hip/hip_runtime.h>

// Problem constants (from reference)
#define F_N 100000
#define C_N 2
#define R_N 500
#define D_N 100            // 25 float4 per feature row
#define NW  3746           // N_WEIGHTS
#define D4  25             // D_N / 4
#define RPAD 512

// BINWIDTHS = {100,200,500,1000,2000,5000}
// BINCUMSTARTS = {0, 2001, 3002, 3403, 3604, 3705}
// Every bw divides 100000:  bin_ix = (c+100000)/bw + start ; alpha = ((c+100000)%bw)/bw

// ---- workspace layout (bytes) ----
// 0      : counts[RPAD]   (int)
// 2048   : starts[RPAD]   (int)
// 4096   : cursor[RPAD]   (int)
// 8192   : sorted_idx[F_N] (int)

__global__ void zero_kernel(int* __restrict__ counts, int* __restrict__ cursor) {
    int t = threadIdx.x;
    if (t < RPAD) { counts[t] = 0; cursor[t] = 0; }
}

__global__ void count_kernel(const int* __restrict__ region_ids, int* __restrict__ counts) {
    int f = blockIdx.x * blockDim.x + threadIdx.x;
    if (f < F_N) atomicAdd(&counts[region_ids[f]], 1);
}

__global__ void scan_kernel(const int* __restrict__ counts, int* __restrict__ starts) {
    if (threadIdx.x == 0 && blockIdx.x == 0) {
        int acc = 0;
        for (int r = 0; r < R_N; ++r) { starts[r] = acc; acc += counts[r]; }
    }
}

__global__ void scatter_kernel(const int* __restrict__ region_ids,
                               const int* __restrict__ starts,
                               int* __restrict__ cursor,
                               int* __restrict__ sorted_idx) {
    int f = blockIdx.x * blockDim.x + threadIdx.x;
    if (f < F_N) {
        int r = region_ids[f];
        int pos = starts[r] + atomicAdd(&cursor[r], 1);
        sorted_idx[pos] = f;
    }
}

__global__ __launch_bounds__(256) void spline_enc_kernel(
    const int*   __restrict__ coords,      // (F, 2) int32
    const int*   __restrict__ region_ids,  // (F,)  int32
    const float* __restrict__ W,           // (R, NW, D) fp32
    const float* __restrict__ bias,        // (R, D) fp32
    const int*   __restrict__ sorted_idx,  // (F,)  region-sorted feature ids
    float*       __restrict__ out)         // (F, D) fp32
{
    const int gid = blockIdx.x * blockDim.x + threadIdx.x;
    const int sp = gid / D4;               // sorted position
    const int j  = gid % D4;
    if (sp >= F_N) return;

    const int f = sorted_idx[sp];
    const int r = region_ids[f];

    int c0 = coords[2 * f];
    int c1 = coords[2 * f + 1];
    c0 = min(max(c0, -100000), 99999);
    c1 = min(max(c1, -100000), 99999);
    const unsigned u0 = (unsigned)(c0 + 100000);
    const unsigned u1 = (unsigned)(c1 + 100000);

    const float4* __restrict__ Wr =
        (const float4*)(W + (size_t)r * ((size_t)NW * D_N));
    const float4* __restrict__ br =
        (const float4*)(bias + (size_t)r * D_N);

    float4 acc = br[j];

    const unsigned bws[6]    = {100u, 200u, 500u, 1000u, 2000u, 5000u};
    const int      starts[6] = {0, 2001, 3002, 3403, 3604, 3705};

#pragma unroll
    for (int s = 0; s < 6; ++s) {
        const unsigned bw = bws[s];
        const float inv_bw = 1.0f / (float)bw;
        const int st = starts[s];
#pragma unroll
        for (int c = 0; c < 2; ++c) {
            const unsigned u = (c == 0) ? u0 : u1;
            const unsigned q = u / bw;          // constant divisor -> magic mul
            const unsigned rem = u - q * bw;
            const float alpha = (float)rem * inv_bw;
            const float oma = 1.0f - alpha;
            const size_t row = (size_t)(q + (unsigned)st) * D4 + j;
            const float4 w0 = Wr[row];
            const float4 w1 = Wr[row + D4];
            acc.x = fmaf(w0.x, oma, acc.x);
            acc.y = fmaf(w0.y, oma, acc.y);
            acc.z = fmaf(w0.z, oma, acc.z);
            acc.w = fmaf(w0.w, oma, acc.w);
            acc.x = fmaf(w1.x, alpha, acc.x);
            acc.y = fmaf(w1.y, alpha, acc.y);
            acc.z = fmaf(w1.z, alpha, acc.z);
            acc.w = fmaf(w1.w, alpha, acc.w);
        }
    }

    ((float4*)out)[(size_t)f * D4 + j] = acc;
}

extern "C" void kernel_launch(void* const* d_in, const int* in_sizes, int n_in,
                              void* d_out, int out_size, void* d_ws, size_t ws_size,
                              hipStream_t stream) {
    const int*   coords     = (const int*)d_in[0];
    const int*   region_ids = (const int*)d_in[1];
    const float* W          = (const float*)d_in[2];
    const float* bias       = (const float*)d_in[3];
    float*       out        = (float*)d_out;

    char* ws = (char*)d_ws;
    int* counts     = (int*)(ws + 0);
    int* starts     = (int*)(ws + 2048);
    int* cursor     = (int*)(ws + 4096);
    int* sorted_idx = (int*)(ws + 8192);

    const int blk = 256;
    const int gF  = (F_N + blk - 1) / blk;

    zero_kernel<<<1, RPAD, 0, stream>>>(counts, cursor);
    count_kernel<<<gF, blk, 0, stream>>>(region_ids, counts);
    scan_kernel<<<1, 64, 0, stream>>>(counts, starts);
    scatter_kernel<<<gF, blk, 0, stream>>>(region_ids, starts, cursor, sorted_idx);

    const int total = F_N * D4;              // 2,500,000 threads
    const int grid  = (total + blk - 1) / blk;
    spline_enc_kernel<<<grid, blk, 0, stream>>>(coords, region_ids, W, bias,
                                                sorted_idx, out);
}